// Round 5
// baseline (238.841 us; speedup 1.0000x reference)
//
#include <hip/hip_runtime.h>

// B=32, C=64, H=128, W=128, N_KNOTS=65. x is (B,C,H,W) row-major, 33,554,432 floats.
// R5 = exact R2 frame (best: 224.2 us) with ONE knob: loads are plain/cached,
// stores stay nontemporal.
//   - R3 (cached loads AND cached stores) regressed +12 us; theory: the harm is
//     store-side (cached stores allocate 134 MB of write-once output in L2/LLC,
//     paying fill+evict before HBM writeback). nt stores bypass that.
//   - Load side untested alone: cached loads can hit LLC if any input survives
//     the inter-iteration poison fills; nt loads structurally cannot.
// Everything else byte-identical to R2: 8192 blocks, 256 thr, 4 vec4/thread,
// one channel table per block, b128 LDS table of precomputed poly coeffs.
//
// LDS: out = a0 + a1*s + a2*s^2 with
//   a0 = (c0+c1)/2,  a1 = c1-c0,  a2 = (c0-2*c1+c2)/2
// One aligned ds_read_b128 per element; idx Gaussian mod 8 -> uniform banks.
//
// Math equivalence with reference (established in prior rounds):
//   t  = x * inv_g            (exact: g = 2^-3, inv_g = 8)
//   fl = clamp(floor(t), -32, 30) == floor(clamp(x)/g)
//   s  = t - fl               == (x - fl*g)/g   (identical rounding)

typedef float vfloat4 __attribute__((ext_vector_type(4)));

__global__ __launch_bounds__(256) void quad_spline_kernel(
    const vfloat4* __restrict__ x,
    const float*   __restrict__ coeffs,
    const float*   __restrict__ grid_p,
    const int*     __restrict__ zki,
    const int*     __restrict__ size_p,
    vfloat4*       __restrict__ out)
{
    __shared__ vfloat4 lds_a[63];   // (a0, a1, a2, pad) per interval, idx in [0,62]

    const int tid   = threadIdx.x;
    const int vbase = blockIdx.x * 1024 + tid;  // 1024 vec4 per block
    const int c     = (blockIdx.x >> 2) & 63;   // 4 blocks per (b,c) slice

    // Issue all streaming loads FIRST so HBM latency overlaps staging + sync.
    // Cached (non-nt) loads: allow LLC hits on the input stream.
    vfloat4 x0 = x[vbase];
    vfloat4 x1 = x[vbase + 256];
    vfloat4 x2 = x[vbase + 512];
    vfloat4 x3 = x[vbase + 768];

    const float g    = grid_p[0];
    const int   size = size_p[0];
    const int   half = size >> 1;               // 32
    const int   base = zki[c] - half;           // = c * size

    if (tid < 63) {
        float c0 = coeffs[base + tid];
        float c1 = coeffs[base + tid + 1];
        float c2 = coeffs[base + tid + 2];
        vfloat4 a;
        a.x = 0.5f * (c0 + c1);                 // a0
        a.y = c1 - c0;                          // a1
        a.z = 0.5f * ((c0 - c1) + (c2 - c1));   // a2
        a.w = 0.0f;
        lds_a[tid] = a;
    }
    __syncthreads();

    const float inv_g = 1.0f / g;               // exact (g = 0.125)
    const float flo   = -(float)half;           // -32
    const float fhi   =  (float)(half - 2);     //  30

    #define SPLINE(xx, dst)                                            \
    {                                                                  \
        float t   = (xx) * inv_g;                                      \
        float fl  = fminf(fmaxf(floorf(t), flo), fhi);                 \
        int   idx = half + (int)fl;                                    \
        float s   = t - fl;                                            \
        vfloat4 a = lds_a[idx];                                        \
        (dst) = fmaf(s, fmaf(s, a.z, a.y), a.x);                       \
    }

    vfloat4 r0, r1, r2, r3;
    SPLINE(x0.x, r0.x) SPLINE(x0.y, r0.y) SPLINE(x0.z, r0.z) SPLINE(x0.w, r0.w)
    SPLINE(x1.x, r1.x) SPLINE(x1.y, r1.y) SPLINE(x1.z, r1.z) SPLINE(x1.w, r1.w)
    SPLINE(x2.x, r2.x) SPLINE(x2.y, r2.y) SPLINE(x2.z, r2.z) SPLINE(x2.w, r2.w)
    SPLINE(x3.x, r3.x) SPLINE(x3.y, r3.y) SPLINE(x3.z, r3.z) SPLINE(x3.w, r3.w)
    #undef SPLINE

    // nt stores: bypass L2/LLC allocation for the write-once output stream
    // (R3 A/B showed cached stores cost ~+12 us together with cached loads).
    __builtin_nontemporal_store(r0, &out[vbase]);
    __builtin_nontemporal_store(r1, &out[vbase + 256]);
    __builtin_nontemporal_store(r2, &out[vbase + 512]);
    __builtin_nontemporal_store(r3, &out[vbase + 768]);
}

extern "C" void kernel_launch(void* const* d_in, const int* in_sizes, int n_in,
                              void* d_out, int out_size, void* d_ws, size_t ws_size,
                              hipStream_t stream) {
    const vfloat4* x      = (const vfloat4*)d_in[0];
    const float*   coeffs = (const float*)d_in[1];
    const float*   grid_p = (const float*)d_in[2];
    const int*     zki    = (const int*)d_in[3];
    const int*     size_p = (const int*)d_in[4];
    vfloat4*       out    = (vfloat4*)d_out;

    const int n4     = in_sizes[0] / 4;   // 8,388,608 vec4
    const int blocks = n4 / 1024;         // 8192 blocks, 4 vec4 per thread

    quad_spline_kernel<<<blocks, 256, 0, stream>>>(x, coeffs, grid_p, zki, size_p, out);
}

// Round 6
// 224.676 us; speedup vs baseline: 1.0630x; 1.0630x over previous
//
#include <hip/hip_runtime.h>

// B=32, C=64, H=128, W=128, N_KNOTS=65. x is (B,C,H,W) row-major, 33,554,432 floats.
// R6 = exact revert to R2, the measured floor (224.2 us).
//
// Session A/B summary (all single-knob unless noted):
//   - nt loads AND nt stores are both required: cached-both +12 us (R3),
//     cached-loads-only +14.6 us (R5). Poison fills between iterations evict
//     any input LLC residency, so cached loads pay allocation for zero hits.
//   - 4 vec4/thread is the granularity optimum (2: +1.8, 16+ping-pong: +6.2).
//   - ALU/LDS shaving beyond the b128 poly-table is null -> those pipes hide
//     under the memory stream (per-wave: ~256 cyc VALU + ~192 cyc LDS vs
//     ~800 cyc HBM at achievable BW, 32 waves/CU resident).
//
// Structure: 8192 blocks x 256 threads, 4 vec4/thread; block sits in ONE
// channel => one 63-entry float4 LDS table of precomputed poly coefficients:
//   out = a0 + a1*s + a2*s^2
//   a0 = (c0+c1)/2,  a1 = c1-c0,  a2 = (c0-2*c1+c2)/2
// One aligned ds_read_b128 per element; idx Gaussian mod 8 -> uniform banks.
//
// Math equivalence with reference:
//   t  = x * inv_g            (exact: g = 2^-3, inv_g = 8)
//   fl = clamp(floor(t), -32, 30) == floor(clamp(x)/g)
//   s  = t - fl               == (x - fl*g)/g   (identical rounding)

typedef float vfloat4 __attribute__((ext_vector_type(4)));

__global__ __launch_bounds__(256) void quad_spline_kernel(
    const vfloat4* __restrict__ x,
    const float*   __restrict__ coeffs,
    const float*   __restrict__ grid_p,
    const int*     __restrict__ zki,
    const int*     __restrict__ size_p,
    vfloat4*       __restrict__ out)
{
    __shared__ vfloat4 lds_a[63];   // (a0, a1, a2, pad) per interval, idx in [0,62]

    const int tid   = threadIdx.x;
    const int vbase = blockIdx.x * 1024 + tid;  // 1024 vec4 per block
    const int c     = (blockIdx.x >> 2) & 63;   // 4 blocks per (b,c) slice

    // Issue all streaming loads FIRST so HBM latency overlaps staging + sync.
    vfloat4 x0 = __builtin_nontemporal_load(&x[vbase]);
    vfloat4 x1 = __builtin_nontemporal_load(&x[vbase + 256]);
    vfloat4 x2 = __builtin_nontemporal_load(&x[vbase + 512]);
    vfloat4 x3 = __builtin_nontemporal_load(&x[vbase + 768]);

    const float g    = grid_p[0];
    const int   size = size_p[0];
    const int   half = size >> 1;               // 32
    const int   base = zki[c] - half;           // = c * size

    if (tid < 63) {
        float c0 = coeffs[base + tid];
        float c1 = coeffs[base + tid + 1];
        float c2 = coeffs[base + tid + 2];
        vfloat4 a;
        a.x = 0.5f * (c0 + c1);                 // a0
        a.y = c1 - c0;                          // a1
        a.z = 0.5f * ((c0 - c1) + (c2 - c1));   // a2
        a.w = 0.0f;
        lds_a[tid] = a;
    }
    __syncthreads();

    const float inv_g = 1.0f / g;               // exact (g = 0.125)
    const float flo   = -(float)half;           // -32
    const float fhi   =  (float)(half - 2);     //  30

    #define SPLINE(xx, dst)                                            \
    {                                                                  \
        float t   = (xx) * inv_g;                                      \
        float fl  = fminf(fmaxf(floorf(t), flo), fhi);                 \
        int   idx = half + (int)fl;                                    \
        float s   = t - fl;                                            \
        vfloat4 a = lds_a[idx];                                        \
        (dst) = fmaf(s, fmaf(s, a.z, a.y), a.x);                       \
    }

    vfloat4 r0, r1, r2, r3;
    SPLINE(x0.x, r0.x) SPLINE(x0.y, r0.y) SPLINE(x0.z, r0.z) SPLINE(x0.w, r0.w)
    SPLINE(x1.x, r1.x) SPLINE(x1.y, r1.y) SPLINE(x1.z, r1.z) SPLINE(x1.w, r1.w)
    SPLINE(x2.x, r2.x) SPLINE(x2.y, r2.y) SPLINE(x2.z, r2.z) SPLINE(x2.w, r2.w)
    SPLINE(x3.x, r3.x) SPLINE(x3.y, r3.y) SPLINE(x3.z, r3.z) SPLINE(x3.w, r3.w)
    #undef SPLINE

    __builtin_nontemporal_store(r0, &out[vbase]);
    __builtin_nontemporal_store(r1, &out[vbase + 256]);
    __builtin_nontemporal_store(r2, &out[vbase + 512]);
    __builtin_nontemporal_store(r3, &out[vbase + 768]);
}

extern "C" void kernel_launch(void* const* d_in, const int* in_sizes, int n_in,
                              void* d_out, int out_size, void* d_ws, size_t ws_size,
                              hipStream_t stream) {
    const vfloat4* x      = (const vfloat4*)d_in[0];
    const float*   coeffs = (const float*)d_in[1];
    const float*   grid_p = (const float*)d_in[2];
    const int*     zki    = (const int*)d_in[3];
    const int*     size_p = (const int*)d_in[4];
    vfloat4*       out    = (vfloat4*)d_out;

    const int n4     = in_sizes[0] / 4;   // 8,388,608 vec4
    const int blocks = n4 / 1024;         // 8192 blocks, 4 vec4 per thread

    quad_spline_kernel<<<blocks, 256, 0, stream>>>(x, coeffs, grid_p, zki, size_p, out);
}